// Round 4
// baseline (308.749 us; speedup 1.0000x reference)
//
#include <hip/hip_runtime.h>

#define CRF_B 512
#define CRF_S 512
#define CRF_T 64
#define CRF_MID 256   // forward computes A_0..A_MID ; backward computes Bv_MID

// Two waves per batch element (block = 128 threads) — R1's proven structure.
//   wave 0: forward  A_i[j]  = (sum_t A_{i-1}[t] * ET[t][j]) * exp(logit_i[j])
//   wave 1: backward Bv_i[t] = sum_j ET[t][j] * exp(logit_{i+1}[j]) * Bv_{i+1}[j]
// Combine: Z = A_MID . Bv_MID via LDS,  logZ = log(.) + (K_f + K_b)*ln2.
//
// R4 changes vs R1 (R3's s_waitcnt(0) accident MEASURED the per-step stall as
// ~700 cyc of global-load latency -> the dominant cost is prefetch depth 1):
//  1. Logits prefetch deepened to 5 steps (p0..p4 rotate, statically renamed
//     under unroll). Load-to-use distance ~5 steps > ~900 cyc HBM latency, so
//     the per-step vmcnt wait is satisfied on arrival.
//  2. Readlane broadcast hoisted in blocks of 16 (16x v_readlane -> SGPR temps
//     -> 16x FMA): moves any VALU-writes-SGPR -> VALU-reads-SGPR wait states
//     out of the dependence window.
//  3. No LDS and no explicit waitcnt intrinsics in the inner loop — compiler
//     manages vmcnt/lgkmcnt (the R3 intrinsic drained vmcnt and killed the
//     pipeline).
//
// Linear-space power-of-2 renorm per chain (proven absmax=0): k = exponent of
// lane0's value, folded into the off-critical-path multiplier; K accumulates.
#define RLFMA16(AI, ET, T0)                                                    \
  do {                                                                         \
    int _s0 = __builtin_amdgcn_readlane(AI, (T0) + 0);                         \
    int _s1 = __builtin_amdgcn_readlane(AI, (T0) + 1);                         \
    int _s2 = __builtin_amdgcn_readlane(AI, (T0) + 2);                         \
    int _s3 = __builtin_amdgcn_readlane(AI, (T0) + 3);                         \
    int _s4 = __builtin_amdgcn_readlane(AI, (T0) + 4);                         \
    int _s5 = __builtin_amdgcn_readlane(AI, (T0) + 5);                         \
    int _s6 = __builtin_amdgcn_readlane(AI, (T0) + 6);                         \
    int _s7 = __builtin_amdgcn_readlane(AI, (T0) + 7);                         \
    int _s8 = __builtin_amdgcn_readlane(AI, (T0) + 8);                         \
    int _s9 = __builtin_amdgcn_readlane(AI, (T0) + 9);                         \
    int _sA = __builtin_amdgcn_readlane(AI, (T0) + 10);                        \
    int _sB = __builtin_amdgcn_readlane(AI, (T0) + 11);                        \
    int _sC = __builtin_amdgcn_readlane(AI, (T0) + 12);                        \
    int _sD = __builtin_amdgcn_readlane(AI, (T0) + 13);                        \
    int _sE = __builtin_amdgcn_readlane(AI, (T0) + 14);                        \
    int _sF = __builtin_amdgcn_readlane(AI, (T0) + 15);                        \
    f0 = fmaf(__int_as_float(_s0), ET[(T0) + 0], f0);                          \
    f1 = fmaf(__int_as_float(_s1), ET[(T0) + 1], f1);                          \
    f2 = fmaf(__int_as_float(_s2), ET[(T0) + 2], f2);                          \
    f3 = fmaf(__int_as_float(_s3), ET[(T0) + 3], f3);                          \
    f0 = fmaf(__int_as_float(_s4), ET[(T0) + 4], f0);                          \
    f1 = fmaf(__int_as_float(_s5), ET[(T0) + 5], f1);                          \
    f2 = fmaf(__int_as_float(_s6), ET[(T0) + 6], f2);                          \
    f3 = fmaf(__int_as_float(_s7), ET[(T0) + 7], f3);                          \
    f0 = fmaf(__int_as_float(_s8), ET[(T0) + 8], f0);                          \
    f1 = fmaf(__int_as_float(_s9), ET[(T0) + 9], f1);                          \
    f2 = fmaf(__int_as_float(_sA), ET[(T0) + 10], f2);                         \
    f3 = fmaf(__int_as_float(_sB), ET[(T0) + 11], f3);                         \
    f0 = fmaf(__int_as_float(_sC), ET[(T0) + 12], f0);                         \
    f1 = fmaf(__int_as_float(_sD), ET[(T0) + 13], f1);                         \
    f2 = fmaf(__int_as_float(_sE), ET[(T0) + 14], f2);                         \
    f3 = fmaf(__int_as_float(_sF), ET[(T0) + 15], f3);                         \
  } while (0)

__global__ __launch_bounds__(128, 1) void crf_fused_kernel(
    const float* __restrict__ logits,   // [B,S,T]
    const int*   __restrict__ tags_raw, // [B,S] int32 OR int64 (runtime-detected)
    const float* __restrict__ trans,    // [T,T]
    const float* __restrict__ start_t,  // [T]
    const float* __restrict__ end_t,    // [T]
    float* __restrict__ out)            // [1], pre-zeroed
{
    const int b   = blockIdx.x;
    const int tid = threadIdx.x;
    const int j   = tid & 63;   // lane
    const int w   = tid >> 6;   // wave id: 0 = forward, 1 = backward

    __shared__ float shBv[CRF_T];  // backward vector at MID
    __shared__ float shNum[2];     // per-wave numerator partial
    __shared__ int   shK[2];       // per-wave renorm exponent sum

    // ---- detect int64 tags: little-endian pairs -> odd 32-bit words all 0 ----
    bool is64 = true;
    #pragma unroll
    for (int ww = 1; ww < 64; ww += 2) is64 = is64 && (tags_raw[ww] == 0);

    const float* lb = logits + (size_t)b * CRF_S * CRF_T;
    const int tbase = b * CRF_S;

    // ---- numerator: 128 threads, positions i = tid, tid+128, ... ----
    float num = 0.f;
    #pragma unroll
    for (int kk = 0; kk < CRF_S / 128; ++kk) {
        int i = kk * 128 + tid;
        int ti = is64 ? tags_raw[(size_t)(tbase + i) * 2] : tags_raw[tbase + i];
        num += lb[i * CRF_T + ti];                       // emission, all i
        if (i == 0) {
            num += start_t[ti];
        } else {
            int tp = is64 ? tags_raw[(size_t)(tbase + i - 1) * 2]
                          : tags_raw[tbase + i - 1];
            num += trans[tp * CRF_T + ti];               // transition, i>=1
        }
        if (i == CRF_S - 1) num += end_t[ti];
    }
    #pragma unroll
    for (int m = 32; m >= 1; m >>= 1) num += __shfl_xor(num, m, 64);
    if (j == 0) shNum[w] = num;

    int K = 0;
    float vec;  // this wave's end-of-loop 64-vector element

    if (w == 0) {
        // ================= forward: A_0 .. A_MID =================
        float et[CRF_T];
        #pragma unroll
        for (int t = 0; t < CRF_T; ++t) et[t] = __expf(trans[t * CRF_T + j]); // ET column j

        float a = __expf(start_t[j] + lb[j]);     // A_0
        float elog = __expf(lb[1 * CRF_T + j]);   // exp(logits[1]) for step 1
        float p0 = lb[2 * CRF_T + j];             // logits[i+1] pipeline, depth 5
        float p1 = lb[3 * CRF_T + j];
        float p2 = lb[4 * CRF_T + j];
        float p3 = lb[5 * CRF_T + j];
        float p4 = lb[6 * CRF_T + j];

        #pragma unroll 2
        for (int i = 1; i <= CRF_MID; ++i) {
            // renorm factor from lane 0's exponent (1/step, hidden under FMAs)
            unsigned mf = (unsigned)__builtin_amdgcn_readfirstlane(__float_as_int(a));
            int k = (int)(mf >> 23) - 127;
            K += k;
            float mult = elog * __int_as_float((unsigned)(127 - k) << 23);  // elog * 2^-k

            int ai = __float_as_int(a);
            float f0 = 0.f, f1 = 0.f, f2 = 0.f, f3 = 0.f;
            RLFMA16(ai, et, 0);
            RLFMA16(ai, et, 16);
            RLFMA16(ai, et, 32);
            RLFMA16(ai, et, 48);
            a = ((f0 + f1) + (f2 + f3)) * mult;   // A_i

            elog = __expf(p0);                    // exp(logits[i+1]) for next step
            p0 = p1; p1 = p2; p2 = p3; p3 = p4;
            p4 = lb[(i + 6) * CRF_T + j];         // max idx 262 < 512, in bounds
        }
        vec = a;   // A_MID[j], scaled by 2^-K
    } else {
        // ================= backward: Bv_{S-1} .. Bv_MID =================
        float et[CRF_T];
        #pragma unroll
        for (int t = 0; t < CRF_T; ++t) et[t] = __expf(trans[j * CRF_T + t]); // ET row j

        float bv = __expf(end_t[j]);                       // Bv_{S-1}
        float elog = __expf(lb[(CRF_S - 1) * CRF_T + j]);  // exp(logits[511]) for i=510
        float p0 = lb[(CRF_S - 2) * CRF_T + j];            // logits[i] pipeline, depth 5
        float p1 = lb[(CRF_S - 3) * CRF_T + j];
        float p2 = lb[(CRF_S - 4) * CRF_T + j];
        float p3 = lb[(CRF_S - 5) * CRF_T + j];
        float p4 = lb[(CRF_S - 6) * CRF_T + j];

        #pragma unroll 2
        for (int i = CRF_S - 2; i >= CRF_MID; --i) {
            // c = Bv_{i+1} * exp(logits[i+1]) * 2^-k
            unsigned mb = (unsigned)__builtin_amdgcn_readfirstlane(__float_as_int(bv));
            int k = (int)(mb >> 23) - 127;
            K += k;
            float c = bv * (elog * __int_as_float((unsigned)(127 - k) << 23));

            int ai = __float_as_int(c);
            float f0 = 0.f, f1 = 0.f, f2 = 0.f, f3 = 0.f;
            RLFMA16(ai, et, 0);
            RLFMA16(ai, et, 16);
            RLFMA16(ai, et, 32);
            RLFMA16(ai, et, 48);
            bv = (f0 + f1) + (f2 + f3);           // Bv_i

            elog = __expf(p0);                    // exp(logits[i]) for next step
            p0 = p1; p1 = p2; p2 = p3; p3 = p4;
            p4 = lb[(i - 6) * CRF_T + j];         // min idx 250 >= 0, in bounds
        }
        vec = bv;  // Bv_MID[j], scaled by 2^-K
    }

    if (j == 0) shK[w] = K;
    if (w == 1) shBv[j] = vec;
    __syncthreads();

    if (w == 0) {
        // ---- Z = A_MID . Bv_MID ----
        float v = vec * shBv[j];
        #pragma unroll
        for (int m = 32; m >= 1; m >>= 1) v += __shfl_xor(v, m, 64);
        if (j == 0) {
            float logZ = __logf(v) + (float)(shK[0] + shK[1]) * 0.69314718055994531f;
            atomicAdd(out, (shNum[0] + shNum[1]) - logZ);
        }
    }
}

extern "C" void kernel_launch(void* const* d_in, const int* in_sizes, int n_in,
                              void* d_out, int out_size, void* d_ws, size_t ws_size,
                              hipStream_t stream) {
    const float* logits  = (const float*)d_in[0];
    const int*   tags    = (const int*)d_in[1];
    // d_in[2] = mask — all ones by construction, unused
    const float* trans   = (const float*)d_in[3];
    const float* start_t = (const float*)d_in[4];
    const float* end_t   = (const float*)d_in[5];
    float* out = (float*)d_out;

    hipMemsetAsync(out, 0, sizeof(float) * (size_t)out_size, stream);
    crf_fused_kernel<<<dim3(CRF_B), dim3(128), 0, stream>>>(
        logits, tags, trans, start_t, end_t, out);
}

// Round 5
// 203.854 us; speedup vs baseline: 1.5146x; 1.5146x over previous
//
#include <hip/hip_runtime.h>

#define CRF_B 512
#define CRF_S 512
#define CRF_T 64
#define CRF_MID 256   // forward computes A_0..A_MID ; backward computes Bv_MID

// Two waves per batch element (block = 128 threads) — R1's proven skeleton.
//   wave 0: forward  A_i[j]  = (sum_t A_{i-1}[t] * ET[t][j]) * exp(logit_i[j])
//   wave 1: backward Bv_i[t] = sum_j ET[t][j] * exp(logit_{i+1}[j]) * Bv_{i+1}[j]
// Combine: Z = A_MID . Bv_MID via LDS,  logZ = log(.) + (K_f + K_b)*ln2.
//
// R5: the measured per-step stall (R3's accidental vmcnt(0) drain = +690 cyc)
// is global-load latency. Fix it STRUCTURALLY, not via rotating prefetch regs
// (R4 showed the compiler's vmcnt tracking collapses on those):
//   * logits staged in LDS tiles of 16 rows (4 KB) via global_load_lds
//     (dwordx4, wave-uniform dest base + lane*16 — linear layout, guide §5),
//     double-buffered per direction. Each wave stages its OWN tiles; no
//     cross-wave barriers.
//   * counted wait: s_waitcnt vmcnt(4) once per 16 steps (next tile's 4 loads
//     stay in flight across ~16*550 cyc >> 900-cyc HBM latency). Never a
//     full drain in the steady state.
//   * inner-loop logits read = ds_read_b32 lane-linear (2-way alias = free),
//     issued at step start, consumed ~300 cyc later at step end -> hidden.
//   * FMA block: R1's verbatim 4-accumulator readlane pattern (best codegen).
__global__ __launch_bounds__(128, 1) void crf_fused_kernel(
    const float* __restrict__ logits,   // [B,S,T]
    const int*   __restrict__ tags_raw, // [B,S] int32 OR int64 (runtime-detected)
    const float* __restrict__ trans,    // [T,T]
    const float* __restrict__ start_t,  // [T]
    const float* __restrict__ end_t,    // [T]
    float* __restrict__ out)            // [1], pre-zeroed
{
    const int b   = blockIdx.x;
    const int tid = threadIdx.x;
    const int j   = tid & 63;   // lane
    const int w   = tid >> 6;   // wave id: 0 = forward, 1 = backward

    __shared__ __align__(16) float tf[2][16][CRF_T];   // forward logits tiles (8 KB)
    __shared__ __align__(16) float tb2[2][16][CRF_T];  // backward logits tiles (8 KB)
    __shared__ float shBv[CRF_T];  // backward vector at MID
    __shared__ float shNum[2];     // per-wave numerator partial
    __shared__ int   shK[2];       // per-wave renorm exponent sum

    // ---- detect int64 tags: little-endian pairs -> odd 32-bit words all 0 ----
    bool is64 = true;
    #pragma unroll
    for (int ww = 1; ww < 64; ww += 2) is64 = is64 && (tags_raw[ww] == 0);

    const float* lb = logits + (size_t)b * CRF_S * CRF_T;
    const int tbase = b * CRF_S;

    // ---- numerator: 128 threads, positions i = tid, tid+128, ... ----
    float num = 0.f;
    #pragma unroll
    for (int kk = 0; kk < CRF_S / 128; ++kk) {
        int i = kk * 128 + tid;
        int ti = is64 ? tags_raw[(size_t)(tbase + i) * 2] : tags_raw[tbase + i];
        num += lb[i * CRF_T + ti];                       // emission, all i
        if (i == 0) {
            num += start_t[ti];
        } else {
            int tp = is64 ? tags_raw[(size_t)(tbase + i - 1) * 2]
                          : tags_raw[tbase + i - 1];
            num += trans[tp * CRF_T + ti];               // transition, i>=1
        }
        if (i == CRF_S - 1) num += end_t[ti];
    }
    #pragma unroll
    for (int m = 32; m >= 1; m >>= 1) num += __shfl_xor(num, m, 64);
    if (j == 0) shNum[w] = num;

    // stage one 4 KB tile (16 rows x 256 B) into LDS: 4x global_load_lds_dwordx4.
    // LDS dest is wave-uniform base; HW writes lane l's 16 B at base + l*16.
    #define STAGE4K(GSRC, LDST)                                                   \
        do {                                                                      \
            const char* _g = (const char*)(GSRC) + (j << 4);                      \
            char* _l = (char*)(LDST);                                             \
            __builtin_amdgcn_global_load_lds(                                     \
                (const __attribute__((address_space(1))) void*)(_g + 0),          \
                (__attribute__((address_space(3))) void*)(_l + 0), 16, 0, 0);     \
            __builtin_amdgcn_global_load_lds(                                     \
                (const __attribute__((address_space(1))) void*)(_g + 1024),       \
                (__attribute__((address_space(3))) void*)(_l + 1024), 16, 0, 0);  \
            __builtin_amdgcn_global_load_lds(                                     \
                (const __attribute__((address_space(1))) void*)(_g + 2048),       \
                (__attribute__((address_space(3))) void*)(_l + 2048), 16, 0, 0);  \
            __builtin_amdgcn_global_load_lds(                                     \
                (const __attribute__((address_space(1))) void*)(_g + 3072),       \
                (__attribute__((address_space(3))) void*)(_l + 3072), 16, 0, 0);  \
        } while (0)

    #define WAITV4 asm volatile("s_waitcnt vmcnt(4)" ::: "memory")
    #define WAITV0 asm volatile("s_waitcnt vmcnt(0)" ::: "memory")

    // R1's verbatim inner matvec: readlane broadcast + 4 accumulators.
    #define MATVEC64(AI, ET, F0, F1, F2, F3)                                              \
        do {                                                                              \
            _Pragma("unroll")                                                             \
            for (int tt = 0; tt < CRF_T; tt += 4) {                                       \
                F0 = fmaf(__int_as_float(__builtin_amdgcn_readlane(AI, tt + 0)), ET[tt + 0], F0); \
                F1 = fmaf(__int_as_float(__builtin_amdgcn_readlane(AI, tt + 1)), ET[tt + 1], F1); \
                F2 = fmaf(__int_as_float(__builtin_amdgcn_readlane(AI, tt + 2)), ET[tt + 2], F2); \
                F3 = fmaf(__int_as_float(__builtin_amdgcn_readlane(AI, tt + 3)), ET[tt + 3], F3); \
            }                                                                             \
        } while (0)

    int K = 0;
    float vec;  // this wave's end-of-loop 64-vector element

    if (w == 0) {
        // ================= forward: A_0 .. A_MID =================
        float et[CRF_T];
        #pragma unroll
        for (int t = 0; t < CRF_T; ++t) et[t] = __expf(trans[t * CRF_T + j]); // ET column j

        float a = __expf(start_t[j] + lb[j]);     // A_0 (row 0, direct global)

        STAGE4K(lb + 1 * CRF_T, tf[0]);           // tile 0: rows 1..16
        STAGE4K(lb + 17 * CRF_T, tf[1]);          // tile 1: rows 17..32

        for (int t = 0; t < 16; ++t) {            // tile t: steps i = 16t+1 .. 16t+16
            if (t < 15) { WAITV4; } else { WAITV0; }
            const int buf = t & 1;
            #pragma unroll 2
            for (int r = 0; r < 16; ++r) {
                float lg = tf[buf][r][j];         // ds_read, consumed at step end

                unsigned mf = (unsigned)__builtin_amdgcn_readfirstlane(__float_as_int(a));
                int k = (int)(mf >> 23) - 127;
                K += k;
                float scale = __int_as_float((unsigned)(127 - k) << 23);  // 2^-k

                int ai = __float_as_int(a);
                float f0 = 0.f, f1 = 0.f, f2 = 0.f, f3 = 0.f;
                MATVEC64(ai, et, f0, f1, f2, f3);

                float mult = __expf(lg) * scale;  // lg needed only here (~300 cyc later)
                a = ((f0 + f1) + (f2 + f3)) * mult;
            }
            if (t < 14) STAGE4K(lb + (16 * (t + 2) + 1) * CRF_T, tf[buf]);  // tile t+2
        }
        vec = a;   // A_MID[j], scaled by 2^-K
    } else {
        // ================= backward: Bv_{S-1} .. Bv_MID =================
        float et[CRF_T];
        #pragma unroll
        for (int t = 0; t < CRF_T; ++t) et[t] = __expf(trans[j * CRF_T + t]); // ET row j

        float bv = __expf(end_t[j]);                       // Bv_{S-1}
        float elog = __expf(lb[(CRF_S - 1) * CRF_T + j]);  // exp(row 511), step n=1

        STAGE4K(lb + 496 * CRF_T, tb2[0]);        // tile 0: rows 496..511
        STAGE4K(lb + 480 * CRF_T, tb2[1]);        // tile 1: rows 480..495

        // full tiles t = 0..14: steps n = 16t+1 .. 16t+16, row(n) = 512-n,
        // in-tile idx = 15 - ((n-1)&15)  (descending 15..0)
        for (int t = 0; t < 15; ++t) {
            WAITV4;
            const int buf = t & 1;
            if (t > 0) elog = __expf(tb2[buf][15][j]);     // first row of tile t
            #pragma unroll 2
            for (int r = 0; r < 16; ++r) {
                unsigned mb = (unsigned)__builtin_amdgcn_readfirstlane(__float_as_int(bv));
                int k = (int)(mb >> 23) - 127;
                K += k;
                float c = bv * (elog * __int_as_float((unsigned)(127 - k) << 23));

                int ci = __float_as_int(c);
                float f0 = 0.f, f1 = 0.f, f2 = 0.f, f3 = 0.f;
                MATVEC64(ci, et, f0, f1, f2, f3);
                bv = (f0 + f1) + (f2 + f3);

                if (r < 15) elog = __expf(tb2[buf][14 - r][j]);  // next step's row
            }
            if (t < 14) STAGE4K(lb + (496 - 16 * (t + 2)) * CRF_T, tb2[buf]);  // tile t+2
        }
        // tail: tile 15 (buf=1), rows 271..257 = idx 15..1, 15 steps (n=241..255)
        WAITV0;
        elog = __expf(tb2[1][15][j]);
        #pragma unroll 2
        for (int r = 0; r < 15; ++r) {
            unsigned mb = (unsigned)__builtin_amdgcn_readfirstlane(__float_as_int(bv));
            int k = (int)(mb >> 23) - 127;
            K += k;
            float c = bv * (elog * __int_as_float((unsigned)(127 - k) << 23));

            int ci = __float_as_int(c);
            float f0 = 0.f, f1 = 0.f, f2 = 0.f, f3 = 0.f;
            MATVEC64(ci, et, f0, f1, f2, f3);
            bv = (f0 + f1) + (f2 + f3);

            if (r < 14) elog = __expf(tb2[1][14 - r][j]);
        }
        vec = bv;  // Bv_MID[j], scaled by 2^-K
    }

    if (j == 0) shK[w] = K;
    if (w == 1) shBv[j] = vec;
    __syncthreads();

    if (w == 0) {
        // ---- Z = A_MID . Bv_MID ----
        float v = vec * shBv[j];
        #pragma unroll
        for (int m = 32; m >= 1; m >>= 1) v += __shfl_xor(v, m, 64);
        if (j == 0) {
            float logZ = __logf(v) + (float)(shK[0] + shK[1]) * 0.69314718055994531f;
            atomicAdd(out, (shNum[0] + shNum[1]) - logZ);
        }
    }
}

extern "C" void kernel_launch(void* const* d_in, const int* in_sizes, int n_in,
                              void* d_out, int out_size, void* d_ws, size_t ws_size,
                              hipStream_t stream) {
    const float* logits  = (const float*)d_in[0];
    const int*   tags    = (const int*)d_in[1];
    // d_in[2] = mask — all ones by construction, unused
    const float* trans   = (const float*)d_in[3];
    const float* start_t = (const float*)d_in[4];
    const float* end_t   = (const float*)d_in[5];
    float* out = (float*)d_out;

    hipMemsetAsync(out, 0, sizeof(float) * (size_t)out_size, stream);
    crf_fused_kernel<<<dim3(CRF_B), dim3(128), 0, stream>>>(
        logits, tags, trans, start_t, end_t, out);
}